// Round 5
// baseline (175.452 us; speedup 1.0000x reference)
//
#include <hip/hip_runtime.h>
#include <math.h>

#define Bb   4
#define Nn   2048
#define Dd   256
#define Hh   4
#define HDd  64
#define BN   (Bb * Nn)

typedef float v4f __attribute__((ext_vector_type(4)));
typedef short v8s __attribute__((ext_vector_type(8)));

__device__ __forceinline__ unsigned rne_bf16(float f) {
    unsigned u = __float_as_uint(f);
    u += 0x7fffu + ((u >> 16) & 1u);
    return u >> 16;
}

// ---------------------------------------------------------------------------
// Kernel 1: role-split grid of 1024 blocks (UNCHANGED from v5).
//   bid even -> gemm block g=bid>>1 ; bid odd -> adj->bitmask compress.
// ---------------------------------------------------------------------------
__global__ __launch_bounds__(256, 2) void k_gemm(const float* __restrict__ x,
                                                 const float* __restrict__ W,
                                                 const float* __restrict__ a_src,
                                                 const float* __restrict__ a_dst,
                                                 const float* __restrict__ adj,
                                                 unsigned short* __restrict__ hbf,
                                                 float* __restrict__ ssrc,
                                                 float* __restrict__ sdst,
                                                 unsigned long long* __restrict__ bitadj) {
    __shared__ __align__(16) unsigned short xs[2][64 * 72];  // hi, lo  (T reuses xs)
    __shared__ __align__(16) unsigned short wsm[2][64 * 72];
    __shared__ float asd[128];

    const int bid0 = (int)blockIdx.x;
    if (bid0 & 1) {
        const int gw = (bid0 >> 1) * 4 + ((int)threadIdx.x >> 6);
        const int lane = (int)threadIdx.x & 63;
#pragma unroll 1
        for (int w = gw * 4; w < 262144; w += 2048 * 4) {
            float v0 = adj[(size_t)((w + 0) >> 5) * 2048 + ((w + 0) & 31) * 64 + lane];
            float v1 = adj[(size_t)((w + 1) >> 5) * 2048 + ((w + 1) & 31) * 64 + lane];
            float v2 = adj[(size_t)((w + 2) >> 5) * 2048 + ((w + 2) & 31) * 64 + lane];
            float v3 = adj[(size_t)((w + 3) >> 5) * 2048 + ((w + 3) & 31) * 64 + lane];
            unsigned long long m0 = __ballot(v0 != 0.0f);
            unsigned long long m1 = __ballot(v1 != 0.0f);
            unsigned long long m2 = __ballot(v2 != 0.0f);
            unsigned long long m3 = __ballot(v3 != 0.0f);
            if (lane == 0) {
                bitadj[w + 0] = m0;
                bitadj[w + 1] = m1;
                bitadj[w + 2] = m2;
                bitadj[w + 3] = m3;
            }
        }
        return;
    }

    const int g = bid0 >> 1;                       // [0,512)
    const int head = (g >> 2) & 3;
    const int mtile = (g & 3) + 4 * (g >> 4);
    const int tid = threadIdx.x;
    const int m0 = mtile * 64;
    const int n0 = head * 64;
    const int b = m0 >> 11;
    const int i0loc = m0 & 2047;

    if (tid < 128) {
        int sel = tid >> 6, d = tid & 63;
        asd[tid] = sel ? a_dst[n0 + d] : a_src[n0 + d];
    }

    const int wv = tid >> 6, ln = tid & 63, l15 = ln & 15, l4 = ln >> 4;
    const int mh = wv >> 1, nh = wv & 1;
    const int srow = tid >> 2, kq = (tid & 3) * 16;

    v4f acc[2][2];
#pragma unroll
    for (int gg = 0; gg < 2; ++gg)
#pragma unroll
        for (int t = 0; t < 2; ++t) acc[gg][t] = (v4f){0.f, 0.f, 0.f, 0.f};

    for (int st = 0; st < 4; ++st) {
        const int k0 = st * 64;
        __syncthreads();
        {
            float xf[16], wf[16];
            const float* xp = x + (size_t)(m0 + srow) * Dd + k0 + kq;
            const float* wp = W + (size_t)(n0 + srow) * Dd + k0 + kq;
#pragma unroll
            for (int q = 0; q < 4; ++q) {
                *(float4*)&xf[q * 4] = *(const float4*)(xp + q * 4);
                *(float4*)&wf[q * 4] = *(const float4*)(wp + q * 4);
            }
            unsigned xh[8], xl[8], wh[8], wl[8];
#pragma unroll
            for (int j = 0; j < 8; ++j) {
                unsigned h0 = rne_bf16(xf[2 * j]), h1 = rne_bf16(xf[2 * j + 1]);
                float l0 = xf[2 * j] - __uint_as_float(h0 << 16);
                float l1 = xf[2 * j + 1] - __uint_as_float(h1 << 16);
                xh[j] = h0 | (h1 << 16);
                xl[j] = rne_bf16(l0) | (rne_bf16(l1) << 16);
                unsigned g0 = rne_bf16(wf[2 * j]), g1 = rne_bf16(wf[2 * j + 1]);
                float m0f = wf[2 * j] - __uint_as_float(g0 << 16);
                float m1f = wf[2 * j + 1] - __uint_as_float(g1 << 16);
                wh[j] = g0 | (g1 << 16);
                wl[j] = rne_bf16(m0f) | (rne_bf16(m1f) << 16);
            }
            *(uint4*)(xs[0] + srow * 72 + kq)     = make_uint4(xh[0], xh[1], xh[2], xh[3]);
            *(uint4*)(xs[0] + srow * 72 + kq + 8) = make_uint4(xh[4], xh[5], xh[6], xh[7]);
            *(uint4*)(xs[1] + srow * 72 + kq)     = make_uint4(xl[0], xl[1], xl[2], xl[3]);
            *(uint4*)(xs[1] + srow * 72 + kq + 8) = make_uint4(xl[4], xl[5], xl[6], xl[7]);
            *(uint4*)(wsm[0] + srow * 72 + kq)     = make_uint4(wh[0], wh[1], wh[2], wh[3]);
            *(uint4*)(wsm[0] + srow * 72 + kq + 8) = make_uint4(wh[4], wh[5], wh[6], wh[7]);
            *(uint4*)(wsm[1] + srow * 72 + kq)     = make_uint4(wl[0], wl[1], wl[2], wl[3]);
            *(uint4*)(wsm[1] + srow * 72 + kq + 8) = make_uint4(wl[4], wl[5], wl[6], wl[7]);
        }
        __syncthreads();
        {
            v8s ah[2][2], al[2][2], bh_[2][2], bl_[2][2];
#pragma unroll
            for (int gg = 0; gg < 2; ++gg)
#pragma unroll
                for (int kh = 0; kh < 2; ++kh) {
                    int ro = (mh * 32 + gg * 16 + l15) * 72 + kh * 32 + l4 * 8;
                    ah[gg][kh] = *(const v8s*)(xs[0] + ro);
                    al[gg][kh] = *(const v8s*)(xs[1] + ro);
                }
#pragma unroll
            for (int t = 0; t < 2; ++t)
#pragma unroll
                for (int kh = 0; kh < 2; ++kh) {
                    int ro = (nh * 32 + t * 16 + l15) * 72 + kh * 32 + l4 * 8;
                    bh_[t][kh] = *(const v8s*)(wsm[0] + ro);
                    bl_[t][kh] = *(const v8s*)(wsm[1] + ro);
                }
#pragma unroll
            for (int gg = 0; gg < 2; ++gg)
#pragma unroll
                for (int t = 0; t < 2; ++t)
#pragma unroll
                    for (int kh = 0; kh < 2; ++kh) {
                        acc[gg][t] = __builtin_amdgcn_mfma_f32_16x16x32_bf16(ah[gg][kh], bh_[t][kh], acc[gg][t], 0, 0, 0);
                        acc[gg][t] = __builtin_amdgcn_mfma_f32_16x16x32_bf16(al[gg][kh], bh_[t][kh], acc[gg][t], 0, 0, 0);
                        acc[gg][t] = __builtin_amdgcn_mfma_f32_16x16x32_bf16(ah[gg][kh], bl_[t][kh], acc[gg][t], 0, 0, 0);
                    }
        }
    }

    __syncthreads();
    float* T = (float*)&xs[0][0];   // 64*67*4 = 17168 B
#pragma unroll
    for (int gg = 0; gg < 2; ++gg)
#pragma unroll
        for (int t = 0; t < 2; ++t)
#pragma unroll
            for (int r = 0; r < 4; ++r) {
                int d = nh * 32 + t * 16 + l15;
                int m = mh * 32 + gg * 16 + l4 * 4 + r;
                T[d * 67 + m] = acc[gg][t][r];
            }
    __syncthreads();
    if (tid < 128) {
        int m = tid & 63, sel = tid >> 6;
        float s = 0.f;
#pragma unroll
        for (int d = 0; d < 64; ++d) s += T[d * 67 + m] * asd[sel * 64 + d];
        (sel ? sdst : ssrc)[(size_t)head * BN + (size_t)b * Nn + i0loc + m] = s;
        int dloc = tid >> 1, jhh = tid & 1;
        const float* row = T + dloc * 67 + jhh * 32;
        unsigned pk[16];
#pragma unroll
        for (int jj = 0; jj < 16; ++jj)
            pk[jj] = rne_bf16(row[jj * 2]) | (rne_bf16(row[jj * 2 + 1]) << 16);
        unsigned short* dst = hbf +
            ((size_t)((b * 64 + (i0loc >> 5) + jhh) * 256 + head * HDd + dloc)) * 32;
        uint4* d4 = (uint4*)dst;
        d4[0] = make_uint4(pk[0], pk[1], pk[2], pk[3]);
        d4[1] = make_uint4(pk[4], pk[5], pk[6], pk[7]);
        d4[2] = make_uint4(pk[8], pk[9], pk[10], pk[11]);
        d4[3] = make_uint4(pk[12], pk[13], pk[14], pk[15]);
    }
}

// ---------------------------------------------------------------------------
// Kernel 2 (v6): register-lean wave split so the B prefetch SURVIVES regalloc.
// v5 lesson: any structure with 8 live B-frags/step dies at the 64-VGPR
// allocation (loads get issued load->use->use serial, ~200cy naked L2 latency
// each; WRITE_SIZE showed spill traffic). v6 wave = (head-of-hp, i-sub, d-half):
// i-tile 16 x d-tiles 2, walks ALL 64 j-chunks itself. Per step: 1 generated
// A-frag, TWO loaded B-frags (8 VGPR), 3 MFMA. Double-buffered B = 16 VGPR;
// whole pipeline ~60 VGPR -> fits. No jh acc-combine; z (ones-MFMA, summed
// over all j by the dh=0 wave) shared to the dh=1 twin via 256B LDS.
// Block covers (b, hp, 32 i-rows); grid 512, XCD-bijective: xcd=bid&7,
// b=xcd>>1, hp=xcd&1 -> per-XCD set = hbf half-plane + bitadj plane, L2-fit.
// dtab (exp-hoist) kept from v5, halved to hp's 2 heads = 32 KB.
// Gen chain bit-identical to v5.
// ---------------------------------------------------------------------------
__global__ __launch_bounds__(512, 4) void k_aggr(const unsigned short* __restrict__ hbf,
                                                 const unsigned long long* __restrict__ bitadj,
                                                 const float* __restrict__ ssrc,
                                                 const float* __restrict__ sdst,
                                                 float* __restrict__ out) {
    __shared__ __align__(16) float dtab[2 * 2048 * 2];   // 32 KB: [hloc][j][{e1,e2}]
    __shared__ __align__(16) float zsh[2][2][16];        // 256 B: [hloc][isub][row]

    const int tid = threadIdx.x;
    const int bid = (int)blockIdx.x;
    const int xcd = bid & 7;
    const int b   = xcd >> 1;              // one b per XCD pair
    const int hp  = xcd & 1;               // head pair on its own XCD
    const int itile = bid >> 3;            // [0,64) -> 32 i-rows

    const int wv   = tid >> 6;
    const int hloc = wv >> 2;              // 0..1
    const int h    = hp * 2 + hloc;
    const int isub = (wv >> 1) & 1;        // i-subtile of 16
    const int dh   = wv & 1;               // d-half (2 d-tiles)
    const int ln = tid & 63, l15 = ln & 15, l4 = ln >> 4;

    // ---- build d-table once for hp's 2 heads: (hloc,j) -> (exp(sd), exp(.2 sd))
    for (int q = tid; q < 1024; q += 512) {
        int hh = q >> 9, j4 = (q & 511) * 4;
        float4 sv = *(const float4*)(sdst + (size_t)(hp * 2 + hh) * BN + (size_t)b * Nn + j4);
        float4 o0 = make_float4(__expf(sv.x), __expf(0.2f * sv.x),
                                __expf(sv.y), __expf(0.2f * sv.y));
        float4 o1 = make_float4(__expf(sv.z), __expf(0.2f * sv.z),
                                __expf(sv.w), __expf(0.2f * sv.w));
        *(float4*)&dtab[(hh * 2048 + j4) * 2]     = o0;
        *(float4*)&dtab[(hh * 2048 + j4) * 2 + 4] = o1;
    }

    const int irow = itile * 32 + isub * 16 + l15;     // lane's A-row (m = l15)
    const float ss = ssrc[(size_t)h * BN + (size_t)b * Nn + irow];
    const float c1 = __expf(ss), c2 = __expf(0.2f * ss);
    const unsigned char* ajr = (const unsigned char*)bitadj +
        ((size_t)b * Nn + irow) * 256;
    const int dg0 = h * HDd + dh * 32;     // this wave's 2 d-tiles
    const unsigned short* hb0 = hbf +
        ((size_t)b * 64 * 256 + (size_t)(dg0 + l15)) * 32 + l4 * 8;
    const float* dtb = dtab + (hloc * 2048 + l4 * 8) * 2;

    const v8s ones = {0x3F80, 0x3F80, 0x3F80, 0x3F80, 0x3F80, 0x3F80, 0x3F80, 0x3F80};

    v4f acc0 = (v4f){0.f, 0.f, 0.f, 0.f}, acc1 = acc0, zac = acc0;
    v8s b0A, b1A, b0B, b1B;
    unsigned mA, mB;

    __syncthreads();   // dtab ready

#define LOADB(JC_, B0_, B1_) do {                                             \
        const unsigned short* hq_ = hb0 + (size_t)(JC_) * 8192;               \
        B0_ = *(const v8s*)(hq_);                                             \
        B1_ = *(const v8s*)(hq_ + 512);                                       \
    } while (0)

#define LOADM(JC_, M_) do { M_ = ajr[(JC_) * 4 + l4]; } while (0)

    // w = bit ? max(c1*e1, c2*e2) : 0  ==  bit ? exp(max(s,0.2s)) : 0 (v5 chain)
#define GENFRAG(dst, M_, dd_) do {                                            \
        const float4 q0_ = *(const float4*)((dd_) + 0);                       \
        const float4 q1_ = *(const float4*)((dd_) + 4);                       \
        const float4 q2_ = *(const float4*)((dd_) + 8);                       \
        const float4 q3_ = *(const float4*)((dd_) + 12);                      \
        float w0_ = ((M_) & 1u)   ? fmaxf(c1 * q0_.x, c2 * q0_.y) : 0.f;      \
        float w1_ = ((M_) & 2u)   ? fmaxf(c1 * q0_.z, c2 * q0_.w) : 0.f;      \
        float w2_ = ((M_) & 4u)   ? fmaxf(c1 * q1_.x, c2 * q1_.y) : 0.f;      \
        float w3_ = ((M_) & 8u)   ? fmaxf(c1 * q1_.z, c2 * q1_.w) : 0.f;      \
        float w4_ = ((M_) & 16u)  ? fmaxf(c1 * q2_.x, c2 * q2_.y) : 0.f;      \
        float w5_ = ((M_) & 32u)  ? fmaxf(c1 * q2_.z, c2 * q2_.w) : 0.f;      \
        float w6_ = ((M_) & 64u)  ? fmaxf(c1 * q3_.x, c2 * q3_.y) : 0.f;      \
        float w7_ = ((M_) & 128u) ? fmaxf(c1 * q3_.z, c2 * q3_.w) : 0.f;      \
        union { v8s v; unsigned u[4]; } P_;                                   \
        asm("v_cvt_pk_bf16_f32 %0, %1, %2" : "=v"(P_.u[0]) : "v"(w0_), "v"(w1_)); \
        asm("v_cvt_pk_bf16_f32 %0, %1, %2" : "=v"(P_.u[1]) : "v"(w2_), "v"(w3_)); \
        asm("v_cvt_pk_bf16_f32 %0, %1, %2" : "=v"(P_.u[2]) : "v"(w4_), "v"(w5_)); \
        asm("v_cvt_pk_bf16_f32 %0, %1, %2" : "=v"(P_.u[3]) : "v"(w6_), "v"(w7_)); \
        dst = P_.v;                                                           \
    } while (0)

#define STEPX(JC_, M_, B0_, B1_) do {                                         \
        const float* dd_ = dtb + (JC_) * 64;                                  \
        v8s afr_;                                                             \
        GENFRAG(afr_, M_, dd_);                                               \
        acc0 = __builtin_amdgcn_mfma_f32_16x16x32_bf16(afr_, B0_, acc0, 0, 0, 0); \
        acc1 = __builtin_amdgcn_mfma_f32_16x16x32_bf16(afr_, B1_, acc1, 0, 0, 0); \
        zac  = __builtin_amdgcn_mfma_f32_16x16x32_bf16(afr_, ones, zac,  0, 0, 0); \
    } while (0)

    LOADB(0, b0A, b1A);
    LOADM(0, mA);
#pragma unroll 1
    for (int jc = 0; jc < 64; jc += 2) {
        LOADB(jc + 1, b0B, b1B);               // one step ahead of use
        LOADM(jc + 1, mB);
        __builtin_amdgcn_sched_barrier(0);
        STEPX(jc, mA, b0A, b1A);
        LOADB((jc + 2) & 63, b0A, b1A);        // &63: wrap, no OOB
        LOADM((jc + 2) & 63, mA);
        __builtin_amdgcn_sched_barrier(0);
        STEPX(jc + 1, mB, b0B, b1B);
    }

#undef LOADB
#undef LOADM
#undef GENFRAG
#undef STEPX

    // ---- z broadcast (dh0 -> both d-halves), normalize, exclusive store ----
    if (dh == 0 && l15 == 0)
        *(v4f*)&zsh[hloc][isub][l4 * 4] = zac;   // rows l4*4 + r
    __syncthreads();
    const v4f zv = *(const v4f*)&zsh[hloc][isub][l4 * 4];
    float* op = out + ((size_t)b * Nn + itile * 32 + isub * 16 + l4 * 4) * Dd + dg0 + l15;
#pragma unroll
    for (int r = 0; r < 4; ++r) {
        float zi = 1.f / zv[r];
        op[(size_t)r * Dd + 0]  = acc0[r] * zi;
        op[(size_t)r * Dd + 16] = acc1[r] * zi;
    }
}

extern "C" void kernel_launch(void* const* d_in, const int* in_sizes, int n_in,
                              void* d_out, int out_size, void* d_ws, size_t ws_size,
                              hipStream_t stream) {
    const float* x     = (const float*)d_in[0];
    const float* adj   = (const float*)d_in[1];
    const float* W     = (const float*)d_in[2];
    const float* a_src = (const float*)d_in[3];
    const float* a_dst = (const float*)d_in[4];
    float* out = (float*)d_out;

    // ws: hbf 4MB | ssrc [h][bn] 128KB | sdst [h][bn] 128KB | bitadj 2MB
    unsigned short* hbf = (unsigned short*)d_ws;
    float* ssrc = (float*)(hbf + (size_t)Bb * Nn * Dd);
    float* sdst = ssrc + (size_t)Hh * BN;
    unsigned long long* bitadj = (unsigned long long*)(sdst + (size_t)Hh * BN);

    k_gemm<<<dim3(1024), dim3(256), 0, stream>>>(x, W, a_src, a_dst, adj,
                                                 hbf, ssrc, sdst, bitadj);
    k_aggr<<<dim3(512), dim3(512), 0, stream>>>(hbf, bitadj, ssrc, sdst, out);
}

// Round 7
// 175.011 us; speedup vs baseline: 1.0025x; 1.0025x over previous
//
#include <hip/hip_runtime.h>
#include <math.h>

#define Bb   4
#define Nn   2048
#define Dd   256
#define Hh   4
#define HDd  64
#define BN   (Bb * Nn)

typedef float v4f __attribute__((ext_vector_type(4)));
typedef short v8s __attribute__((ext_vector_type(8)));

__device__ __forceinline__ unsigned rne_bf16(float f) {
    unsigned u = __float_as_uint(f);
    u += 0x7fffu + ((u >> 16) & 1u);
    return u >> 16;
}

// ---------------------------------------------------------------------------
// Kernel 1: role-split grid of 1024 blocks (UNCHANGED from v5/v6/v7).
//   bid even -> gemm block g=bid>>1 ; bid odd -> adj->bitmask compress.
// ---------------------------------------------------------------------------
__global__ __launch_bounds__(256, 2) void k_gemm(const float* __restrict__ x,
                                                 const float* __restrict__ W,
                                                 const float* __restrict__ a_src,
                                                 const float* __restrict__ a_dst,
                                                 const float* __restrict__ adj,
                                                 unsigned short* __restrict__ hbf,
                                                 float* __restrict__ ssrc,
                                                 float* __restrict__ sdst,
                                                 unsigned long long* __restrict__ bitadj) {
    __shared__ __align__(16) unsigned short xs[2][64 * 72];  // hi, lo  (T reuses xs)
    __shared__ __align__(16) unsigned short wsm[2][64 * 72];
    __shared__ float asd[128];

    const int bid0 = (int)blockIdx.x;
    if (bid0 & 1) {
        const int gw = (bid0 >> 1) * 4 + ((int)threadIdx.x >> 6);
        const int lane = (int)threadIdx.x & 63;
#pragma unroll 1
        for (int w = gw * 4; w < 262144; w += 2048 * 4) {
            float v0 = adj[(size_t)((w + 0) >> 5) * 2048 + ((w + 0) & 31) * 64 + lane];
            float v1 = adj[(size_t)((w + 1) >> 5) * 2048 + ((w + 1) & 31) * 64 + lane];
            float v2 = adj[(size_t)((w + 2) >> 5) * 2048 + ((w + 2) & 31) * 64 + lane];
            float v3 = adj[(size_t)((w + 3) >> 5) * 2048 + ((w + 3) & 31) * 64 + lane];
            unsigned long long m0 = __ballot(v0 != 0.0f);
            unsigned long long m1 = __ballot(v1 != 0.0f);
            unsigned long long m2 = __ballot(v2 != 0.0f);
            unsigned long long m3 = __ballot(v3 != 0.0f);
            if (lane == 0) {
                bitadj[w + 0] = m0;
                bitadj[w + 1] = m1;
                bitadj[w + 2] = m2;
                bitadj[w + 3] = m3;
            }
        }
        return;
    }

    const int g = bid0 >> 1;                       // [0,512)
    const int head = (g >> 2) & 3;
    const int mtile = (g & 3) + 4 * (g >> 4);
    const int tid = threadIdx.x;
    const int m0 = mtile * 64;
    const int n0 = head * 64;
    const int b = m0 >> 11;
    const int i0loc = m0 & 2047;

    if (tid < 128) {
        int sel = tid >> 6, d = tid & 63;
        asd[tid] = sel ? a_dst[n0 + d] : a_src[n0 + d];
    }

    const int wv = tid >> 6, ln = tid & 63, l15 = ln & 15, l4 = ln >> 4;
    const int mh = wv >> 1, nh = wv & 1;
    const int srow = tid >> 2, kq = (tid & 3) * 16;

    v4f acc[2][2];
#pragma unroll
    for (int gg = 0; gg < 2; ++gg)
#pragma unroll
        for (int t = 0; t < 2; ++t) acc[gg][t] = (v4f){0.f, 0.f, 0.f, 0.f};

    for (int st = 0; st < 4; ++st) {
        const int k0 = st * 64;
        __syncthreads();
        {
            float xf[16], wf[16];
            const float* xp = x + (size_t)(m0 + srow) * Dd + k0 + kq;
            const float* wp = W + (size_t)(n0 + srow) * Dd + k0 + kq;
#pragma unroll
            for (int q = 0; q < 4; ++q) {
                *(float4*)&xf[q * 4] = *(const float4*)(xp + q * 4);
                *(float4*)&wf[q * 4] = *(const float4*)(wp + q * 4);
            }
            unsigned xh[8], xl[8], wh[8], wl[8];
#pragma unroll
            for (int j = 0; j < 8; ++j) {
                unsigned h0 = rne_bf16(xf[2 * j]), h1 = rne_bf16(xf[2 * j + 1]);
                float l0 = xf[2 * j] - __uint_as_float(h0 << 16);
                float l1 = xf[2 * j + 1] - __uint_as_float(h1 << 16);
                xh[j] = h0 | (h1 << 16);
                xl[j] = rne_bf16(l0) | (rne_bf16(l1) << 16);
                unsigned g0 = rne_bf16(wf[2 * j]), g1 = rne_bf16(wf[2 * j + 1]);
                float m0f = wf[2 * j] - __uint_as_float(g0 << 16);
                float m1f = wf[2 * j + 1] - __uint_as_float(g1 << 16);
                wh[j] = g0 | (g1 << 16);
                wl[j] = rne_bf16(m0f) | (rne_bf16(m1f) << 16);
            }
            *(uint4*)(xs[0] + srow * 72 + kq)     = make_uint4(xh[0], xh[1], xh[2], xh[3]);
            *(uint4*)(xs[0] + srow * 72 + kq + 8) = make_uint4(xh[4], xh[5], xh[6], xh[7]);
            *(uint4*)(xs[1] + srow * 72 + kq)     = make_uint4(xl[0], xl[1], xl[2], xl[3]);
            *(uint4*)(xs[1] + srow * 72 + kq + 8) = make_uint4(xl[4], xl[5], xl[6], xl[7]);
            *(uint4*)(wsm[0] + srow * 72 + kq)     = make_uint4(wh[0], wh[1], wh[2], wh[3]);
            *(uint4*)(wsm[0] + srow * 72 + kq + 8) = make_uint4(wh[4], wh[5], wh[6], wh[7]);
            *(uint4*)(wsm[1] + srow * 72 + kq)     = make_uint4(wl[0], wl[1], wl[2], wl[3]);
            *(uint4*)(wsm[1] + srow * 72 + kq + 8) = make_uint4(wl[4], wl[5], wl[6], wl[7]);
        }
        __syncthreads();
        {
            v8s ah[2][2], al[2][2], bh_[2][2], bl_[2][2];
#pragma unroll
            for (int gg = 0; gg < 2; ++gg)
#pragma unroll
                for (int kh = 0; kh < 2; ++kh) {
                    int ro = (mh * 32 + gg * 16 + l15) * 72 + kh * 32 + l4 * 8;
                    ah[gg][kh] = *(const v8s*)(xs[0] + ro);
                    al[gg][kh] = *(const v8s*)(xs[1] + ro);
                }
#pragma unroll
            for (int t = 0; t < 2; ++t)
#pragma unroll
                for (int kh = 0; kh < 2; ++kh) {
                    int ro = (nh * 32 + t * 16 + l15) * 72 + kh * 32 + l4 * 8;
                    bh_[t][kh] = *(const v8s*)(wsm[0] + ro);
                    bl_[t][kh] = *(const v8s*)(wsm[1] + ro);
                }
#pragma unroll
            for (int gg = 0; gg < 2; ++gg)
#pragma unroll
                for (int t = 0; t < 2; ++t)
#pragma unroll
                    for (int kh = 0; kh < 2; ++kh) {
                        acc[gg][t] = __builtin_amdgcn_mfma_f32_16x16x32_bf16(ah[gg][kh], bh_[t][kh], acc[gg][t], 0, 0, 0);
                        acc[gg][t] = __builtin_amdgcn_mfma_f32_16x16x32_bf16(al[gg][kh], bh_[t][kh], acc[gg][t], 0, 0, 0);
                        acc[gg][t] = __builtin_amdgcn_mfma_f32_16x16x32_bf16(ah[gg][kh], bl_[t][kh], acc[gg][t], 0, 0, 0);
                    }
        }
    }

    __syncthreads();
    float* T = (float*)&xs[0][0];   // 64*67*4 = 17168 B
#pragma unroll
    for (int gg = 0; gg < 2; ++gg)
#pragma unroll
        for (int t = 0; t < 2; ++t)
#pragma unroll
            for (int r = 0; r < 4; ++r) {
                int d = nh * 32 + t * 16 + l15;
                int m = mh * 32 + gg * 16 + l4 * 4 + r;
                T[d * 67 + m] = acc[gg][t][r];
            }
    __syncthreads();
    if (tid < 128) {
        int m = tid & 63, sel = tid >> 6;
        float s = 0.f;
#pragma unroll
        for (int d = 0; d < 64; ++d) s += T[d * 67 + m] * asd[sel * 64 + d];
        (sel ? sdst : ssrc)[(size_t)head * BN + (size_t)b * Nn + i0loc + m] = s;
        int dloc = tid >> 1, jhh = tid & 1;
        const float* row = T + dloc * 67 + jhh * 32;
        unsigned pk[16];
#pragma unroll
        for (int jj = 0; jj < 16; ++jj)
            pk[jj] = rne_bf16(row[jj * 2]) | (rne_bf16(row[jj * 2 + 1]) << 16);
        unsigned short* dst = hbf +
            ((size_t)((b * 64 + (i0loc >> 5) + jhh) * 256 + head * HDd + dloc)) * 32;
        uint4* d4 = (uint4*)dst;
        d4[0] = make_uint4(pk[0], pk[1], pk[2], pk[3]);
        d4[1] = make_uint4(pk[4], pk[5], pk[6], pk[7]);
        d4[2] = make_uint4(pk[8], pk[9], pk[10], pk[11]);
        d4[3] = make_uint4(pk[12], pk[13], pk[14], pk[15]);
    }
}

// ---------------------------------------------------------------------------
// Kernel 2 (v8): v7 structure EXACTLY, but __launch_bounds__(512, 6).
// v7 FAIL diagnosis: logic verified isomorphic to passing v6 (bijective
// block map, exact-cover jp walk, correct combine pairing); the only new
// build-level ingredient was the (512,8) 64-VGPR cap on a ~75-VGPR live
// set -> forced spills around the inline-asm cvt_pk + MFMA cluster
// (guide rule #18 regime) -> suspected miscompile/NaN.  v8 gives the
// allocator ~80 VGPRs (no forced spill) and still targets 3 blocks/CU
// = 6 waves/SIMD (v6 had 4).  All indexing identical to v7:
//   block = (b, ONE head, 32 i-rows); grid 1024;
//   8 waves = (isub 2) x (dh 2) x (jp 2), jp walks its j-chunk parity;
//   per step: 1 generated A-frag, 2 loaded B-frags (dbuf), 3 MFMA;
//   jp-partials (acc0,acc1,zac) combined via 12 KB LDS red.
// Gen chain bit-identical to v5/v6.
// ---------------------------------------------------------------------------
__global__ __launch_bounds__(512, 6) void k_aggr(const unsigned short* __restrict__ hbf,
                                                 const unsigned long long* __restrict__ bitadj,
                                                 const float* __restrict__ ssrc,
                                                 const float* __restrict__ sdst,
                                                 float* __restrict__ out) {
    __shared__ __align__(16) float dtab[2048 * 2];   // 16 KB: [j][{e1,e2}], one head
    __shared__ __align__(16) v4f red[4 * 64 * 3];    // 12 KB jp-combine

    const int tid = threadIdx.x;
    const int bid = (int)blockIdx.x;
    const int xcd  = bid & 7;
    const int h    = xcd >> 1;             // one head per XCD pair
    const int bpar = xcd & 1;
    const int q    = bid >> 3;             // 0..127
    const int b    = ((q & 1) << 1) | bpar;
    const int itile = q >> 1;              // 0..63 -> 32 i-rows

    const int wv   = tid >> 6;
    const int isub = (wv >> 2) & 1;        // i-subtile of 16
    const int dh   = (wv >> 1) & 1;        // d-half (2 d-tiles)
    const int jp   = wv & 1;               // j-chunk parity
    const int ln = tid & 63, l15 = ln & 15, l4 = ln >> 4;

    // ---- build d-table once for head h: j -> (exp(sd), exp(.2 sd)) ----
    {
        const int j4 = tid * 4;
        float4 sv = *(const float4*)(sdst + (size_t)h * BN + (size_t)b * Nn + j4);
        float4 o0 = make_float4(__expf(sv.x), __expf(0.2f * sv.x),
                                __expf(sv.y), __expf(0.2f * sv.y));
        float4 o1 = make_float4(__expf(sv.z), __expf(0.2f * sv.z),
                                __expf(sv.w), __expf(0.2f * sv.w));
        *(float4*)&dtab[j4 * 2]     = o0;
        *(float4*)&dtab[j4 * 2 + 4] = o1;
    }

    const int irow = itile * 32 + isub * 16 + l15;     // lane's A-row (m = l15)
    const float ss = ssrc[(size_t)h * BN + (size_t)b * Nn + irow];
    const float c1 = __expf(ss), c2 = __expf(0.2f * ss);
    const unsigned char* ajr = (const unsigned char*)bitadj +
        ((size_t)b * Nn + irow) * 256;
    const int dg0 = h * HDd + dh * 32;     // this wave's 2 d-tiles
    const unsigned short* hb0 = hbf +
        ((size_t)b * 64 * 256 + (size_t)(dg0 + l15)) * 32 + l4 * 8;
    const float* dtb = dtab + l4 * 16;

    const v8s ones = {0x3F80, 0x3F80, 0x3F80, 0x3F80, 0x3F80, 0x3F80, 0x3F80, 0x3F80};

    v4f acc0 = (v4f){0.f, 0.f, 0.f, 0.f}, acc1 = acc0, zac = acc0;
    v8s b0A, b1A, b0B, b1B;
    unsigned mA, mB;

#define LOADB(JC_, B0_, B1_) do {                                             \
        const unsigned short* hq_ = hb0 + (size_t)(JC_) * 8192;               \
        B0_ = *(const v8s*)(hq_);                                             \
        B1_ = *(const v8s*)(hq_ + 512);                                       \
    } while (0)

#define LOADM(JC_, M_) do { M_ = ajr[(JC_) * 4 + l4]; } while (0)

    // w = bit ? max(c1*e1, c2*e2) : 0  ==  bit ? exp(max(s,0.2s)) : 0 (v5 chain)
#define GENFRAG(dst, M_, dd_) do {                                            \
        const float4 q0_ = *(const float4*)((dd_) + 0);                       \
        const float4 q1_ = *(const float4*)((dd_) + 4);                       \
        const float4 q2_ = *(const float4*)((dd_) + 8);                       \
        const float4 q3_ = *(const float4*)((dd_) + 12);                      \
        float w0_ = ((M_) & 1u)   ? fmaxf(c1 * q0_.x, c2 * q0_.y) : 0.f;      \
        float w1_ = ((M_) & 2u)   ? fmaxf(c1 * q0_.z, c2 * q0_.w) : 0.f;      \
        float w2_ = ((M_) & 4u)   ? fmaxf(c1 * q1_.x, c2 * q1_.y) : 0.f;      \
        float w3_ = ((M_) & 8u)   ? fmaxf(c1 * q1_.z, c2 * q1_.w) : 0.f;      \
        float w4_ = ((M_) & 16u)  ? fmaxf(c1 * q2_.x, c2 * q2_.y) : 0.f;      \
        float w5_ = ((M_) & 32u)  ? fmaxf(c1 * q2_.z, c2 * q2_.w) : 0.f;      \
        float w6_ = ((M_) & 64u)  ? fmaxf(c1 * q3_.x, c2 * q3_.y) : 0.f;      \
        float w7_ = ((M_) & 128u) ? fmaxf(c1 * q3_.z, c2 * q3_.w) : 0.f;      \
        union { v8s v; unsigned u[4]; } P_;                                   \
        asm("v_cvt_pk_bf16_f32 %0, %1, %2" : "=v"(P_.u[0]) : "v"(w0_), "v"(w1_)); \
        asm("v_cvt_pk_bf16_f32 %0, %1, %2" : "=v"(P_.u[1]) : "v"(w2_), "v"(w3_)); \
        asm("v_cvt_pk_bf16_f32 %0, %1, %2" : "=v"(P_.u[2]) : "v"(w4_), "v"(w5_)); \
        asm("v_cvt_pk_bf16_f32 %0, %1, %2" : "=v"(P_.u[3]) : "v"(w6_), "v"(w7_)); \
        dst = P_.v;                                                           \
    } while (0)

#define STEPX(JC_, M_, B0_, B1_) do {                                         \
        const float* dd_ = dtb + (JC_) * 64;                                  \
        v8s afr_;                                                             \
        GENFRAG(afr_, M_, dd_);                                               \
        acc0 = __builtin_amdgcn_mfma_f32_16x16x32_bf16(afr_, B0_, acc0, 0, 0, 0); \
        acc1 = __builtin_amdgcn_mfma_f32_16x16x32_bf16(afr_, B1_, acc1, 0, 0, 0); \
        zac  = __builtin_amdgcn_mfma_f32_16x16x32_bf16(afr_, ones, zac,  0, 0, 0); \
    } while (0)

    LOADB(jp, b0A, b1A);
    LOADM(jp, mA);
    __syncthreads();   // dtab ready (prefetch already in flight)

#pragma unroll 1
    for (int s = 0; s < 32; s += 2) {
        const int jc0 = 2 * s + jp;                    // this wave's parity lane
        LOADB(jc0 + 2, b0B, b1B);                      // next step in flight
        LOADM(jc0 + 2, mB);
        __builtin_amdgcn_sched_barrier(0);
        STEPX(jc0, mA, b0A, b1A);
        LOADB((jc0 + 4) & 63, b0A, b1A);               // &63: wrap, no OOB
        LOADM((jc0 + 4) & 63, mA);
        __builtin_amdgcn_sched_barrier(0);
        STEPX(jc0 + 2, mB, b0B, b1B);
    }

#undef LOADB
#undef LOADM
#undef GENFRAG
#undef STEPX

    // ---- jp-combine via LDS; jp=0 waves normalize + store ----
    const int wpair = wv >> 1;             // (isub, dh)
    v4f* rp = red + (wpair * 64 + ln) * 3;
    if (jp) {
        rp[0] = acc0;
        rp[1] = acc1;
        rp[2] = zac;
    }
    __syncthreads();
    if (!jp) {
        acc0 += rp[0];
        acc1 += rp[1];
        zac  += rp[2];
        float* op = out + ((size_t)b * Nn + itile * 32 + isub * 16 + l4 * 4) * Dd + dg0 + l15;
#pragma unroll
        for (int r = 0; r < 4; ++r) {
            float zi = 1.f / zac[r];
            op[(size_t)r * Dd + 0]  = acc0[r] * zi;
            op[(size_t)r * Dd + 16] = acc1[r] * zi;
        }
    }
}

extern "C" void kernel_launch(void* const* d_in, const int* in_sizes, int n_in,
                              void* d_out, int out_size, void* d_ws, size_t ws_size,
                              hipStream_t stream) {
    const float* x     = (const float*)d_in[0];
    const float* adj   = (const float*)d_in[1];
    const float* W     = (const float*)d_in[2];
    const float* a_src = (const float*)d_in[3];
    const float* a_dst = (const float*)d_in[4];
    float* out = (float*)d_out;

    // ws: hbf 4MB | ssrc [h][bn] 128KB | sdst [h][bn] 128KB | bitadj 2MB
    unsigned short* hbf = (unsigned short*)d_ws;
    float* ssrc = (float*)(hbf + (size_t)Bb * Nn * Dd);
    float* sdst = ssrc + (size_t)Hh * BN;
    unsigned long long* bitadj = (unsigned long long*)(sdst + (size_t)Hh * BN);

    k_gemm<<<dim3(1024), dim3(256), 0, stream>>>(x, W, a_src, a_dst, adj,
                                                 hbf, ssrc, sdst, bitadj);
    k_aggr<<<dim3(1024), dim3(512), 0, stream>>>(hbf, bitadj, ssrc, sdst, out);
}

// Round 8
// 138.777 us; speedup vs baseline: 1.2643x; 1.2611x over previous
//
#include <hip/hip_runtime.h>
#include <math.h>

#define Bb   4
#define Nn   2048
#define Dd   256
#define Hh   4
#define HDd  64
#define BN   (Bb * Nn)

typedef float v4f __attribute__((ext_vector_type(4)));
typedef short v8s __attribute__((ext_vector_type(8)));

__device__ __forceinline__ unsigned rne_bf16(float f) {
    unsigned u = __float_as_uint(f);
    u += 0x7fffu + ((u >> 16) & 1u);
    return u >> 16;
}

// ---------------------------------------------------------------------------
// Kernel 1: role-split grid of 1024 blocks (logic unchanged; ONLY the hbf
// pack layout changed).  bid even -> gemm ; bid odd -> adj->bitmask.
// NEW hbf layout: lane-linear B-fragment regions.  Region (b, jb, h) = 4KB
// at shorts ((b*64+jb)*4+h)*2048; within: d-tile dt (0..3) at dt*512, lane
// ln=(l15,l4) at ln*8 shorts = h[d=h*64+dt*16+l15][j=jb*32+l4*8..+8].
// k_aggr can then stage a region with a straight 16B/thread copy and read
// it with conflict-free lane-linear ds_read_b128.
// ---------------------------------------------------------------------------
__global__ __launch_bounds__(256, 2) void k_gemm(const float* __restrict__ x,
                                                 const float* __restrict__ W,
                                                 const float* __restrict__ a_src,
                                                 const float* __restrict__ a_dst,
                                                 const float* __restrict__ adj,
                                                 unsigned short* __restrict__ hbf,
                                                 float* __restrict__ ssrc,
                                                 float* __restrict__ sdst,
                                                 unsigned long long* __restrict__ bitadj) {
    __shared__ __align__(16) unsigned short xs[2][64 * 72];  // hi, lo  (T reuses xs)
    __shared__ __align__(16) unsigned short wsm[2][64 * 72];
    __shared__ float asd[128];

    const int bid0 = (int)blockIdx.x;
    if (bid0 & 1) {
        const int gw = (bid0 >> 1) * 4 + ((int)threadIdx.x >> 6);
        const int lane = (int)threadIdx.x & 63;
#pragma unroll 1
        for (int w = gw * 4; w < 262144; w += 2048 * 4) {
            float v0 = adj[(size_t)((w + 0) >> 5) * 2048 + ((w + 0) & 31) * 64 + lane];
            float v1 = adj[(size_t)((w + 1) >> 5) * 2048 + ((w + 1) & 31) * 64 + lane];
            float v2 = adj[(size_t)((w + 2) >> 5) * 2048 + ((w + 2) & 31) * 64 + lane];
            float v3 = adj[(size_t)((w + 3) >> 5) * 2048 + ((w + 3) & 31) * 64 + lane];
            unsigned long long m0 = __ballot(v0 != 0.0f);
            unsigned long long m1 = __ballot(v1 != 0.0f);
            unsigned long long m2 = __ballot(v2 != 0.0f);
            unsigned long long m3 = __ballot(v3 != 0.0f);
            if (lane == 0) {
                bitadj[w + 0] = m0;
                bitadj[w + 1] = m1;
                bitadj[w + 2] = m2;
                bitadj[w + 3] = m3;
            }
        }
        return;
    }

    const int g = bid0 >> 1;                       // [0,512)
    const int head = (g >> 2) & 3;
    const int mtile = (g & 3) + 4 * (g >> 4);
    const int tid = threadIdx.x;
    const int m0 = mtile * 64;
    const int n0 = head * 64;
    const int b = m0 >> 11;
    const int i0loc = m0 & 2047;

    if (tid < 128) {
        int sel = tid >> 6, d = tid & 63;
        asd[tid] = sel ? a_dst[n0 + d] : a_src[n0 + d];
    }

    const int wv = tid >> 6, ln = tid & 63, l15 = ln & 15, l4 = ln >> 4;
    const int mh = wv >> 1, nh = wv & 1;
    const int srow = tid >> 2, kq = (tid & 3) * 16;

    v4f acc[2][2];
#pragma unroll
    for (int gg = 0; gg < 2; ++gg)
#pragma unroll
        for (int t = 0; t < 2; ++t) acc[gg][t] = (v4f){0.f, 0.f, 0.f, 0.f};

    for (int st = 0; st < 4; ++st) {
        const int k0 = st * 64;
        __syncthreads();
        {
            float xf[16], wf[16];
            const float* xp = x + (size_t)(m0 + srow) * Dd + k0 + kq;
            const float* wp = W + (size_t)(n0 + srow) * Dd + k0 + kq;
#pragma unroll
            for (int q = 0; q < 4; ++q) {
                *(float4*)&xf[q * 4] = *(const float4*)(xp + q * 4);
                *(float4*)&wf[q * 4] = *(const float4*)(wp + q * 4);
            }
            unsigned xh[8], xl[8], wh[8], wl[8];
#pragma unroll
            for (int j = 0; j < 8; ++j) {
                unsigned h0 = rne_bf16(xf[2 * j]), h1 = rne_bf16(xf[2 * j + 1]);
                float l0 = xf[2 * j] - __uint_as_float(h0 << 16);
                float l1 = xf[2 * j + 1] - __uint_as_float(h1 << 16);
                xh[j] = h0 | (h1 << 16);
                xl[j] = rne_bf16(l0) | (rne_bf16(l1) << 16);
                unsigned g0 = rne_bf16(wf[2 * j]), g1 = rne_bf16(wf[2 * j + 1]);
                float m0f = wf[2 * j] - __uint_as_float(g0 << 16);
                float m1f = wf[2 * j + 1] - __uint_as_float(g1 << 16);
                wh[j] = g0 | (g1 << 16);
                wl[j] = rne_bf16(m0f) | (rne_bf16(m1f) << 16);
            }
            *(uint4*)(xs[0] + srow * 72 + kq)     = make_uint4(xh[0], xh[1], xh[2], xh[3]);
            *(uint4*)(xs[0] + srow * 72 + kq + 8) = make_uint4(xh[4], xh[5], xh[6], xh[7]);
            *(uint4*)(xs[1] + srow * 72 + kq)     = make_uint4(xl[0], xl[1], xl[2], xl[3]);
            *(uint4*)(xs[1] + srow * 72 + kq + 8) = make_uint4(xl[4], xl[5], xl[6], xl[7]);
            *(uint4*)(wsm[0] + srow * 72 + kq)     = make_uint4(wh[0], wh[1], wh[2], wh[3]);
            *(uint4*)(wsm[0] + srow * 72 + kq + 8) = make_uint4(wh[4], wh[5], wh[6], wh[7]);
            *(uint4*)(wsm[1] + srow * 72 + kq)     = make_uint4(wl[0], wl[1], wl[2], wl[3]);
            *(uint4*)(wsm[1] + srow * 72 + kq + 8) = make_uint4(wl[4], wl[5], wl[6], wl[7]);
        }
        __syncthreads();
        {
            v8s ah[2][2], al[2][2], bh_[2][2], bl_[2][2];
#pragma unroll
            for (int gg = 0; gg < 2; ++gg)
#pragma unroll
                for (int kh = 0; kh < 2; ++kh) {
                    int ro = (mh * 32 + gg * 16 + l15) * 72 + kh * 32 + l4 * 8;
                    ah[gg][kh] = *(const v8s*)(xs[0] + ro);
                    al[gg][kh] = *(const v8s*)(xs[1] + ro);
                }
#pragma unroll
            for (int t = 0; t < 2; ++t)
#pragma unroll
                for (int kh = 0; kh < 2; ++kh) {
                    int ro = (nh * 32 + t * 16 + l15) * 72 + kh * 32 + l4 * 8;
                    bh_[t][kh] = *(const v8s*)(wsm[0] + ro);
                    bl_[t][kh] = *(const v8s*)(wsm[1] + ro);
                }
#pragma unroll
            for (int gg = 0; gg < 2; ++gg)
#pragma unroll
                for (int t = 0; t < 2; ++t)
#pragma unroll
                    for (int kh = 0; kh < 2; ++kh) {
                        acc[gg][t] = __builtin_amdgcn_mfma_f32_16x16x32_bf16(ah[gg][kh], bh_[t][kh], acc[gg][t], 0, 0, 0);
                        acc[gg][t] = __builtin_amdgcn_mfma_f32_16x16x32_bf16(al[gg][kh], bh_[t][kh], acc[gg][t], 0, 0, 0);
                        acc[gg][t] = __builtin_amdgcn_mfma_f32_16x16x32_bf16(ah[gg][kh], bl_[t][kh], acc[gg][t], 0, 0, 0);
                    }
        }
    }

    __syncthreads();
    float* T = (float*)&xs[0][0];   // 64*67*4 = 17168 B
#pragma unroll
    for (int gg = 0; gg < 2; ++gg)
#pragma unroll
        for (int t = 0; t < 2; ++t)
#pragma unroll
            for (int r = 0; r < 4; ++r) {
                int d = nh * 32 + t * 16 + l15;
                int m = mh * 32 + gg * 16 + l4 * 4 + r;
                T[d * 67 + m] = acc[gg][t][r];
            }
    __syncthreads();
    if (tid < 128) {
        int m = tid & 63, sel = tid >> 6;
        float s = 0.f;
#pragma unroll
        for (int d = 0; d < 64; ++d) s += T[d * 67 + m] * asd[sel * 64 + d];
        (sel ? sdst : ssrc)[(size_t)head * BN + (size_t)b * Nn + i0loc + m] = s;
        // hbf pack -> NEW lane-linear B-frag layout
        int dloc = tid >> 1, jh2 = tid & 1;
        const float* row = T + dloc * 67 + jh2 * 32;
        unsigned pk[16];
#pragma unroll
        for (int jj = 0; jj < 16; ++jj)
            pk[jj] = rne_bf16(row[jj * 2]) | (rne_bf16(row[jj * 2 + 1]) << 16);
        const int jb = (i0loc >> 5) + jh2;
        const int dt = dloc >> 4, fl = dloc & 15;
        unsigned short* rb = hbf +
            ((size_t)((b * 64 + jb) * 4 + head) * 2048 + dt * 512 + fl * 8);
        *(uint4*)(rb + 0 * 128) = make_uint4(pk[0],  pk[1],  pk[2],  pk[3]);
        *(uint4*)(rb + 1 * 128) = make_uint4(pk[4],  pk[5],  pk[6],  pk[7]);
        *(uint4*)(rb + 2 * 128) = make_uint4(pk[8],  pk[9],  pk[10], pk[11]);
        *(uint4*)(rb + 3 * 128) = make_uint4(pk[12], pk[13], pk[14], pk[15]);
    }
}

// ---------------------------------------------------------------------------
// Kernel 2 (v9): LDS-staged B pipeline (prefetch depth costs ~4 VGPR, not 32
// -- ends the 5-round war with the register allocator) + gen amortized x4.
// Block = (b, ONE head, 64 i-rows); grid 512, XCD-bijective (per-XCD ~1.5MB
// L2 set).  8 waves = (isub 4) x (jp 2); wave walks its j-parity (32 rounds),
// covers ALL 4 d-tiles (one gen A-frag feeds 4 acc MFMA + 1 z -- v6/v8 dup'd
// gen per d-half).  Per round: T14 async-split staging of next round's two
// 4KB B-frag regions (16B/thread global load at round TOP behind
// sched_barrier(0); ds_write after compute) -> one barrier per round, data
// always one round ahead.  dtab exp-table (16KB) as v5-v8; jp-partials
// combined via 20KB red.  Gen chain bit-identical to v5-v8.
// ---------------------------------------------------------------------------
__global__ __launch_bounds__(512, 4) void k_aggr(const unsigned short* __restrict__ hbf,
                                                 const unsigned long long* __restrict__ bitadj,
                                                 const float* __restrict__ ssrc,
                                                 const float* __restrict__ sdst,
                                                 float* __restrict__ out) {
    __shared__ __align__(16) unsigned short Btile[2][2][2048];  // 16 KB dbuf x {even,odd} jc
    __shared__ __align__(16) float dtab[2048 * 2];              // 16 KB exp-table
    __shared__ __align__(16) float red[4][64][20];              // 20 KB jp-combine

    const int tid = threadIdx.x;
    const int bid = (int)blockIdx.x;
    const int xcd  = bid & 7;
    const int h    = xcd >> 1;             // one head per XCD pair
    const int bpar = xcd & 1;
    const int q    = bid >> 3;             // 0..63
    const int b    = ((q & 1) << 1) | bpar;
    const int itile = q >> 1;              // 0..31 -> 64 i-rows
    const int i0 = itile * 64;

    const int wv   = tid >> 6;
    const int isub = wv >> 1;              // 0..3 (16 i-rows each)
    const int jp   = wv & 1;               // j-chunk parity
    const int ln = tid & 63, l15 = ln & 15, l4 = ln >> 4;

    // staging role: thread stages one 16B chunk of one region per round
    const int spar = tid >> 8;             // region parity (0/1)
    const int soff = tid & 255;            // chunk index within 4KB

    // ---- build exp-table for head h: j -> (exp(sd), exp(.2 sd)) ----
    {
        const int j4 = tid * 4;
        float4 sv = *(const float4*)(sdst + (size_t)h * BN + (size_t)b * Nn + j4);
        float4 o0 = make_float4(__expf(sv.x), __expf(0.2f * sv.x),
                                __expf(sv.y), __expf(0.2f * sv.y));
        float4 o1 = make_float4(__expf(sv.z), __expf(0.2f * sv.z),
                                __expf(sv.w), __expf(0.2f * sv.w));
        *(float4*)&dtab[j4 * 2]     = o0;
        *(float4*)&dtab[j4 * 2 + 4] = o1;
    }

    const int irow = i0 + isub * 16 + l15;         // lane's A-row (m = l15)
    const float ss = ssrc[(size_t)h * BN + (size_t)b * Nn + irow];
    const float c1 = __expf(ss), c2 = __expf(0.2f * ss);
    const unsigned char* ajr = (const unsigned char*)bitadj +
        ((size_t)b * Nn + irow) * 256;
    // staging source: region (b, jc, h) at shorts ((b*64+jc)*4+h)*2048; +jc*8192
    const unsigned short* sbase = hbf +
        ((size_t)(b * 64 * 4) + h) * 2048 + (size_t)soff * 8;
    const float* dtb = dtab + l4 * 16;

    const v8s ones = {0x3F80, 0x3F80, 0x3F80, 0x3F80, 0x3F80, 0x3F80, 0x3F80, 0x3F80};

    v4f acc0 = (v4f){0.f, 0.f, 0.f, 0.f}, acc1 = acc0, acc2 = acc0, acc3 = acc0, zac = acc0;
    uint4 stg;
    unsigned mA, mB;

    // w = bit ? max(c1*e1, c2*e2) : 0  ==  bit ? exp(max(s,0.2s)) : 0
#define GENFRAG(dst, M_, dd_) do {                                            \
        const float4 q0_ = *(const float4*)((dd_) + 0);                       \
        const float4 q1_ = *(const float4*)((dd_) + 4);                       \
        const float4 q2_ = *(const float4*)((dd_) + 8);                       \
        const float4 q3_ = *(const float4*)((dd_) + 12);                      \
        float w0_ = ((M_) & 1u)   ? fmaxf(c1 * q0_.x, c2 * q0_.y) : 0.f;      \
        float w1_ = ((M_) & 2u)   ? fmaxf(c1 * q0_.z, c2 * q0_.w) : 0.f;      \
        float w2_ = ((M_) & 4u)   ? fmaxf(c1 * q1_.x, c2 * q1_.y) : 0.f;      \
        float w3_ = ((M_) & 8u)   ? fmaxf(c1 * q1_.z, c2 * q1_.w) : 0.f;      \
        float w4_ = ((M_) & 16u)  ? fmaxf(c1 * q2_.x, c2 * q2_.y) : 0.f;      \
        float w5_ = ((M_) & 32u)  ? fmaxf(c1 * q2_.z, c2 * q2_.w) : 0.f;      \
        float w6_ = ((M_) & 64u)  ? fmaxf(c1 * q3_.x, c2 * q3_.y) : 0.f;      \
        float w7_ = ((M_) & 128u) ? fmaxf(c1 * q3_.z, c2 * q3_.w) : 0.f;      \
        union { v8s v; unsigned u[4]; } P_;                                   \
        asm("v_cvt_pk_bf16_f32 %0, %1, %2" : "=v"(P_.u[0]) : "v"(w0_), "v"(w1_)); \
        asm("v_cvt_pk_bf16_f32 %0, %1, %2" : "=v"(P_.u[1]) : "v"(w2_), "v"(w3_)); \
        asm("v_cvt_pk_bf16_f32 %0, %1, %2" : "=v"(P_.u[2]) : "v"(w4_), "v"(w5_)); \
        asm("v_cvt_pk_bf16_f32 %0, %1, %2" : "=v"(P_.u[3]) : "v"(w6_), "v"(w7_)); \
        dst = P_.v;                                                           \
    } while (0)

    // compute one round: jc = this wave's j-chunk; btp = its staged region
#define COMPUTE(JC_, M_, btp) do {                                            \
        const unsigned short* bp_ = (btp);                                    \
        v8s bf0_ = *(const v8s*)(bp_ + 0 * 512 + ln * 8);                     \
        v8s bf1_ = *(const v8s*)(bp_ + 1 * 512 + ln * 8);                     \
        v8s bf2_ = *(const v8s*)(bp_ + 2 * 512 + ln * 8);                     \
        v8s bf3_ = *(const v8s*)(bp_ + 3 * 512 + ln * 8);                     \
        const float* dd_ = dtb + (JC_) * 64;                                  \
        v8s afr_;                                                             \
        GENFRAG(afr_, M_, dd_);                                               \
        acc0 = __builtin_amdgcn_mfma_f32_16x16x32_bf16(afr_, bf0_, acc0, 0, 0, 0); \
        acc1 = __builtin_amdgcn_mfma_f32_16x16x32_bf16(afr_, bf1_, acc1, 0, 0, 0); \
        acc2 = __builtin_amdgcn_mfma_f32_16x16x32_bf16(afr_, bf2_, acc2, 0, 0, 0); \
        acc3 = __builtin_amdgcn_mfma_f32_16x16x32_bf16(afr_, bf3_, acc3, 0, 0, 0); \
        zac  = __builtin_amdgcn_mfma_f32_16x16x32_bf16(afr_, ones, zac,  0, 0, 0); \
    } while (0)

    // ---- prologue: stage round 0 (jc {0,1}) into buf0; first mask ----
    stg = *(const uint4*)(sbase + (size_t)spar * 8192);
    mA = ajr[jp * 4 + l4];
    *(uint4*)&Btile[0][spar][soff * 8] = stg;    // compiler waits vmcnt
    __syncthreads();                             // buf0 + dtab ready

#pragma unroll 1
    for (int rr = 0; rr < 32; rr += 2) {
        // ---- round rr (buf0): compute jc=2*rr+jp; stage round rr+1 -> buf1
        {
            const int sjc = (2 * rr + 2 + spar) & 63;
            stg = *(const uint4*)(sbase + (size_t)sjc * 8192);
            mB = ajr[((2 * rr + 2 + jp) & 63) * 4 + l4];
            __builtin_amdgcn_sched_barrier(0);   // pin loads above compute
            COMPUTE(2 * rr + jp, mA, Btile[0][jp]);
            *(uint4*)&Btile[1][spar][soff * 8] = stg;
            __syncthreads();
        }
        // ---- round rr+1 (buf1): compute jc=2*rr+2+jp; stage rr+2 -> buf0
        {
            const int sjc = (2 * rr + 4 + spar) & 63;   // wraps at rr=30: harmless
            stg = *(const uint4*)(sbase + (size_t)sjc * 8192);
            mA = ajr[((2 * rr + 4 + jp) & 63) * 4 + l4];
            __builtin_amdgcn_sched_barrier(0);
            COMPUTE(2 * rr + 2 + jp, mB, Btile[1][jp]);
            *(uint4*)&Btile[0][spar][soff * 8] = stg;
            __syncthreads();
        }
    }

#undef GENFRAG
#undef COMPUTE

    // ---- jp-combine via LDS; jp=0 waves normalize + exclusive store ----
    if (jp) {
        float* rp = &red[isub][ln][0];
        *(v4f*)(rp + 0)  = acc0;
        *(v4f*)(rp + 4)  = acc1;
        *(v4f*)(rp + 8)  = acc2;
        *(v4f*)(rp + 12) = acc3;
        *(v4f*)(rp + 16) = zac;
    }
    __syncthreads();
    if (!jp) {
        const float* rp = &red[isub][ln][0];
        acc0 += *(const v4f*)(rp + 0);
        acc1 += *(const v4f*)(rp + 4);
        acc2 += *(const v4f*)(rp + 8);
        acc3 += *(const v4f*)(rp + 12);
        zac  += *(const v4f*)(rp + 16);
        float* op = out + ((size_t)b * Nn + i0 + isub * 16 + l4 * 4) * Dd + h * HDd + l15;
#pragma unroll
        for (int r = 0; r < 4; ++r) {
            float zi = 1.f / zac[r];
            op[(size_t)r * Dd + 0]  = acc0[r] * zi;
            op[(size_t)r * Dd + 16] = acc1[r] * zi;
            op[(size_t)r * Dd + 32] = acc2[r] * zi;
            op[(size_t)r * Dd + 48] = acc3[r] * zi;
        }
    }
}

extern "C" void kernel_launch(void* const* d_in, const int* in_sizes, int n_in,
                              void* d_out, int out_size, void* d_ws, size_t ws_size,
                              hipStream_t stream) {
    const float* x     = (const float*)d_in[0];
    const float* adj   = (const float*)d_in[1];
    const float* W     = (const float*)d_in[2];
    const float* a_src = (const float*)d_in[3];
    const float* a_dst = (const float*)d_in[4];
    float* out = (float*)d_out;

    // ws: hbf 4MB | ssrc [h][bn] 128KB | sdst [h][bn] 128KB | bitadj 2MB
    unsigned short* hbf = (unsigned short*)d_ws;
    float* ssrc = (float*)(hbf + (size_t)Bb * Nn * Dd);
    float* sdst = ssrc + (size_t)Hh * BN;
    unsigned long long* bitadj = (unsigned long long*)(sdst + (size_t)Hh * BN);

    k_gemm<<<dim3(1024), dim3(256), 0, stream>>>(x, W, a_src, a_dst, adj,
                                                 hbf, ssrc, sdst, bitadj);
    k_aggr<<<dim3(512), dim3(512), 0, stream>>>(hbf, bitadj, ssrc, sdst, out);
}

// Round 9
// 137.140 us; speedup vs baseline: 1.2794x; 1.0119x over previous
//
#include <hip/hip_runtime.h>
#include <math.h>

#define Bb   4
#define Nn   2048
#define Dd   256
#define Hh   4
#define HDd  64
#define BN   (Bb * Nn)

typedef float v4f __attribute__((ext_vector_type(4)));
typedef short v8s __attribute__((ext_vector_type(8)));

__device__ __forceinline__ unsigned rne_bf16(float f) {
    unsigned u = __float_as_uint(f);
    u += 0x7fffu + ((u >> 16) & 1u);
    return u >> 16;
}

// ---------------------------------------------------------------------------
// Kernel 1: role-split grid of 1024 blocks (UNCHANGED from v9).
//   bid even -> gemm ; bid odd -> adj->bitmask compress.
// hbf layout: lane-linear B-frag regions; region (b,jb,h)=4KB at shorts
// ((b*64+jb)*4+h)*2048; d-tile dt at dt*512; lane ln at ln*8.
// ---------------------------------------------------------------------------
__global__ __launch_bounds__(256, 2) void k_gemm(const float* __restrict__ x,
                                                 const float* __restrict__ W,
                                                 const float* __restrict__ a_src,
                                                 const float* __restrict__ a_dst,
                                                 const float* __restrict__ adj,
                                                 unsigned short* __restrict__ hbf,
                                                 float* __restrict__ ssrc,
                                                 float* __restrict__ sdst,
                                                 unsigned long long* __restrict__ bitadj) {
    __shared__ __align__(16) unsigned short xs[2][64 * 72];  // hi, lo  (T reuses xs)
    __shared__ __align__(16) unsigned short wsm[2][64 * 72];
    __shared__ float asd[128];

    const int bid0 = (int)blockIdx.x;
    if (bid0 & 1) {
        const int gw = (bid0 >> 1) * 4 + ((int)threadIdx.x >> 6);
        const int lane = (int)threadIdx.x & 63;
#pragma unroll 1
        for (int w = gw * 4; w < 262144; w += 2048 * 4) {
            float v0 = adj[(size_t)((w + 0) >> 5) * 2048 + ((w + 0) & 31) * 64 + lane];
            float v1 = adj[(size_t)((w + 1) >> 5) * 2048 + ((w + 1) & 31) * 64 + lane];
            float v2 = adj[(size_t)((w + 2) >> 5) * 2048 + ((w + 2) & 31) * 64 + lane];
            float v3 = adj[(size_t)((w + 3) >> 5) * 2048 + ((w + 3) & 31) * 64 + lane];
            unsigned long long m0 = __ballot(v0 != 0.0f);
            unsigned long long m1 = __ballot(v1 != 0.0f);
            unsigned long long m2 = __ballot(v2 != 0.0f);
            unsigned long long m3 = __ballot(v3 != 0.0f);
            if (lane == 0) {
                bitadj[w + 0] = m0;
                bitadj[w + 1] = m1;
                bitadj[w + 2] = m2;
                bitadj[w + 3] = m3;
            }
        }
        return;
    }

    const int g = bid0 >> 1;                       // [0,512)
    const int head = (g >> 2) & 3;
    const int mtile = (g & 3) + 4 * (g >> 4);
    const int tid = threadIdx.x;
    const int m0 = mtile * 64;
    const int n0 = head * 64;
    const int b = m0 >> 11;
    const int i0loc = m0 & 2047;

    if (tid < 128) {
        int sel = tid >> 6, d = tid & 63;
        asd[tid] = sel ? a_dst[n0 + d] : a_src[n0 + d];
    }

    const int wv = tid >> 6, ln = tid & 63, l15 = ln & 15, l4 = ln >> 4;
    const int mh = wv >> 1, nh = wv & 1;
    const int srow = tid >> 2, kq = (tid & 3) * 16;

    v4f acc[2][2];
#pragma unroll
    for (int gg = 0; gg < 2; ++gg)
#pragma unroll
        for (int t = 0; t < 2; ++t) acc[gg][t] = (v4f){0.f, 0.f, 0.f, 0.f};

    for (int st = 0; st < 4; ++st) {
        const int k0 = st * 64;
        __syncthreads();
        {
            float xf[16], wf[16];
            const float* xp = x + (size_t)(m0 + srow) * Dd + k0 + kq;
            const float* wp = W + (size_t)(n0 + srow) * Dd + k0 + kq;
#pragma unroll
            for (int q = 0; q < 4; ++q) {
                *(float4*)&xf[q * 4] = *(const float4*)(xp + q * 4);
                *(float4*)&wf[q * 4] = *(const float4*)(wp + q * 4);
            }
            unsigned xh[8], xl[8], wh[8], wl[8];
#pragma unroll
            for (int j = 0; j < 8; ++j) {
                unsigned h0 = rne_bf16(xf[2 * j]), h1 = rne_bf16(xf[2 * j + 1]);
                float l0 = xf[2 * j] - __uint_as_float(h0 << 16);
                float l1 = xf[2 * j + 1] - __uint_as_float(h1 << 16);
                xh[j] = h0 | (h1 << 16);
                xl[j] = rne_bf16(l0) | (rne_bf16(l1) << 16);
                unsigned g0 = rne_bf16(wf[2 * j]), g1 = rne_bf16(wf[2 * j + 1]);
                float m0f = wf[2 * j] - __uint_as_float(g0 << 16);
                float m1f = wf[2 * j + 1] - __uint_as_float(g1 << 16);
                wh[j] = g0 | (g1 << 16);
                wl[j] = rne_bf16(m0f) | (rne_bf16(m1f) << 16);
            }
            *(uint4*)(xs[0] + srow * 72 + kq)     = make_uint4(xh[0], xh[1], xh[2], xh[3]);
            *(uint4*)(xs[0] + srow * 72 + kq + 8) = make_uint4(xh[4], xh[5], xh[6], xh[7]);
            *(uint4*)(xs[1] + srow * 72 + kq)     = make_uint4(xl[0], xl[1], xl[2], xl[3]);
            *(uint4*)(xs[1] + srow * 72 + kq + 8) = make_uint4(xl[4], xl[5], xl[6], xl[7]);
            *(uint4*)(wsm[0] + srow * 72 + kq)     = make_uint4(wh[0], wh[1], wh[2], wh[3]);
            *(uint4*)(wsm[0] + srow * 72 + kq + 8) = make_uint4(wh[4], wh[5], wh[6], wh[7]);
            *(uint4*)(wsm[1] + srow * 72 + kq)     = make_uint4(wl[0], wl[1], wl[2], wl[3]);
            *(uint4*)(wsm[1] + srow * 72 + kq + 8) = make_uint4(wl[4], wl[5], wl[6], wl[7]);
        }
        __syncthreads();
        {
            v8s ah[2][2], al[2][2], bh_[2][2], bl_[2][2];
#pragma unroll
            for (int gg = 0; gg < 2; ++gg)
#pragma unroll
                for (int kh = 0; kh < 2; ++kh) {
                    int ro = (mh * 32 + gg * 16 + l15) * 72 + kh * 32 + l4 * 8;
                    ah[gg][kh] = *(const v8s*)(xs[0] + ro);
                    al[gg][kh] = *(const v8s*)(xs[1] + ro);
                }
#pragma unroll
            for (int t = 0; t < 2; ++t)
#pragma unroll
                for (int kh = 0; kh < 2; ++kh) {
                    int ro = (nh * 32 + t * 16 + l15) * 72 + kh * 32 + l4 * 8;
                    bh_[t][kh] = *(const v8s*)(wsm[0] + ro);
                    bl_[t][kh] = *(const v8s*)(wsm[1] + ro);
                }
#pragma unroll
            for (int gg = 0; gg < 2; ++gg)
#pragma unroll
                for (int t = 0; t < 2; ++t)
#pragma unroll
                    for (int kh = 0; kh < 2; ++kh) {
                        acc[gg][t] = __builtin_amdgcn_mfma_f32_16x16x32_bf16(ah[gg][kh], bh_[t][kh], acc[gg][t], 0, 0, 0);
                        acc[gg][t] = __builtin_amdgcn_mfma_f32_16x16x32_bf16(al[gg][kh], bh_[t][kh], acc[gg][t], 0, 0, 0);
                        acc[gg][t] = __builtin_amdgcn_mfma_f32_16x16x32_bf16(ah[gg][kh], bl_[t][kh], acc[gg][t], 0, 0, 0);
                    }
        }
    }

    __syncthreads();
    float* T = (float*)&xs[0][0];   // 64*67*4 = 17168 B
#pragma unroll
    for (int gg = 0; gg < 2; ++gg)
#pragma unroll
        for (int t = 0; t < 2; ++t)
#pragma unroll
            for (int r = 0; r < 4; ++r) {
                int d = nh * 32 + t * 16 + l15;
                int m = mh * 32 + gg * 16 + l4 * 4 + r;
                T[d * 67 + m] = acc[gg][t][r];
            }
    __syncthreads();
    if (tid < 128) {
        int m = tid & 63, sel = tid >> 6;
        float s = 0.f;
#pragma unroll
        for (int d = 0; d < 64; ++d) s += T[d * 67 + m] * asd[sel * 64 + d];
        (sel ? sdst : ssrc)[(size_t)head * BN + (size_t)b * Nn + i0loc + m] = s;
        // hbf pack -> lane-linear B-frag layout
        int dloc = tid >> 1, jh2 = tid & 1;
        const float* row = T + dloc * 67 + jh2 * 32;
        unsigned pk[16];
#pragma unroll
        for (int jj = 0; jj < 16; ++jj)
            pk[jj] = rne_bf16(row[jj * 2]) | (rne_bf16(row[jj * 2 + 1]) << 16);
        const int jb = (i0loc >> 5) + jh2;
        const int dt = dloc >> 4, fl = dloc & 15;
        unsigned short* rb = hbf +
            ((size_t)((b * 64 + jb) * 4 + head) * 2048 + dt * 512 + fl * 8);
        *(uint4*)(rb + 0 * 128) = make_uint4(pk[0],  pk[1],  pk[2],  pk[3]);
        *(uint4*)(rb + 1 * 128) = make_uint4(pk[4],  pk[5],  pk[6],  pk[7]);
        *(uint4*)(rb + 2 * 128) = make_uint4(pk[8],  pk[9],  pk[10], pk[11]);
        *(uint4*)(rb + 3 * 128) = make_uint4(pk[12], pk[13], pk[14], pk[15]);
    }
}

// ---------------------------------------------------------------------------
// Kernel 2 (v10): v9's LDS-staged pipeline with SUPER-ROUND staging.
// v9 synced every round (~150 cy work/barrier -> barrier skew dominated).
// v10 stages 4 regions (16 KB, 32 B/thread) per sync; each wave computes
// 2 rounds per barrier -> 16 barriers (was 32), 2x work per sync, same
// register economy (stg = 8 VGPR).  Masks prefetched a super-round ahead.
// All v9 indexing/gen/epilogue unchanged (verified).  LDS 68 KB.
// ---------------------------------------------------------------------------
__global__ __launch_bounds__(512, 4) void k_aggr(const unsigned short* __restrict__ hbf,
                                                 const unsigned long long* __restrict__ bitadj,
                                                 const float* __restrict__ ssrc,
                                                 const float* __restrict__ sdst,
                                                 float* __restrict__ out) {
    __shared__ __align__(16) unsigned short Btile[2][4][2048];  // 32 KB dbuf x 4 regions
    __shared__ __align__(16) float dtab[2048 * 2];              // 16 KB exp-table
    __shared__ __align__(16) float red[4][64][20];              // 20 KB jp-combine

    const int tid = threadIdx.x;
    const int bid = (int)blockIdx.x;
    const int xcd  = bid & 7;
    const int h    = xcd >> 1;             // one head per XCD pair
    const int bpar = xcd & 1;
    const int q    = bid >> 3;             // 0..63
    const int b    = ((q & 1) << 1) | bpar;
    const int itile = q >> 1;              // 0..31 -> 64 i-rows
    const int i0 = itile * 64;

    const int wv   = tid >> 6;
    const int isub = wv >> 1;              // 0..3 (16 i-rows each)
    const int jp   = wv & 1;               // j-chunk parity
    const int ln = tid & 63, l15 = ln & 15, l4 = ln >> 4;

    // staging role: thread stages 32B of one region per super-round
    const int ri   = (tid >> 7) & 3;       // region index 0..3
    const int soff = (tid & 127) * 16;     // shorts within region

    // ---- build exp-table for head h: j -> (exp(sd), exp(.2 sd)) ----
    {
        const int j4 = tid * 4;
        float4 sv = *(const float4*)(sdst + (size_t)h * BN + (size_t)b * Nn + j4);
        float4 o0 = make_float4(__expf(sv.x), __expf(0.2f * sv.x),
                                __expf(sv.y), __expf(0.2f * sv.y));
        float4 o1 = make_float4(__expf(sv.z), __expf(0.2f * sv.z),
                                __expf(sv.w), __expf(0.2f * sv.w));
        *(float4*)&dtab[j4 * 2]     = o0;
        *(float4*)&dtab[j4 * 2 + 4] = o1;
    }

    const int irow = i0 + isub * 16 + l15;         // lane's A-row (m = l15)
    const float ss = ssrc[(size_t)h * BN + (size_t)b * Nn + irow];
    const float c1 = __expf(ss), c2 = __expf(0.2f * ss);
    const unsigned char* ajr = (const unsigned char*)bitadj +
        ((size_t)b * Nn + irow) * 256;
    // staging source: region jc at base + jc*8192 shorts
    const unsigned short* sb2 = hbf +
        ((size_t)(b * 64 * 4) + h) * 2048 + soff;
    const float* dtb = dtab + l4 * 16;

    const v8s ones = {0x3F80, 0x3F80, 0x3F80, 0x3F80, 0x3F80, 0x3F80, 0x3F80, 0x3F80};

    v4f acc0 = (v4f){0.f, 0.f, 0.f, 0.f}, acc1 = acc0, acc2 = acc0, acc3 = acc0, zac = acc0;
    uint4 stg0, stg1;
    unsigned mA, mB;

    // w = bit ? max(c1*e1, c2*e2) : 0  ==  bit ? exp(max(s,0.2s)) : 0
#define GENFRAG(dst, M_, dd_) do {                                            \
        const float4 q0_ = *(const float4*)((dd_) + 0);                       \
        const float4 q1_ = *(const float4*)((dd_) + 4);                       \
        const float4 q2_ = *(const float4*)((dd_) + 8);                       \
        const float4 q3_ = *(const float4*)((dd_) + 12);                      \
        float w0_ = ((M_) & 1u)   ? fmaxf(c1 * q0_.x, c2 * q0_.y) : 0.f;      \
        float w1_ = ((M_) & 2u)   ? fmaxf(c1 * q0_.z, c2 * q0_.w) : 0.f;      \
        float w2_ = ((M_) & 4u)   ? fmaxf(c1 * q1_.x, c2 * q1_.y) : 0.f;      \
        float w3_ = ((M_) & 8u)   ? fmaxf(c1 * q1_.z, c2 * q1_.w) : 0.f;      \
        float w4_ = ((M_) & 16u)  ? fmaxf(c1 * q2_.x, c2 * q2_.y) : 0.f;      \
        float w5_ = ((M_) & 32u)  ? fmaxf(c1 * q2_.z, c2 * q2_.w) : 0.f;      \
        float w6_ = ((M_) & 64u)  ? fmaxf(c1 * q3_.x, c2 * q3_.y) : 0.f;      \
        float w7_ = ((M_) & 128u) ? fmaxf(c1 * q3_.z, c2 * q3_.w) : 0.f;      \
        union { v8s v; unsigned u[4]; } P_;                                   \
        asm("v_cvt_pk_bf16_f32 %0, %1, %2" : "=v"(P_.u[0]) : "v"(w0_), "v"(w1_)); \
        asm("v_cvt_pk_bf16_f32 %0, %1, %2" : "=v"(P_.u[1]) : "v"(w2_), "v"(w3_)); \
        asm("v_cvt_pk_bf16_f32 %0, %1, %2" : "=v"(P_.u[2]) : "v"(w4_), "v"(w5_)); \
        asm("v_cvt_pk_bf16_f32 %0, %1, %2" : "=v"(P_.u[3]) : "v"(w6_), "v"(w7_)); \
        dst = P_.v;                                                           \
    } while (0)

#define COMPUTE(JC_, M_, btp) do {                                            \
        const unsigned short* bp_ = (btp);                                    \
        v8s bf0_ = *(const v8s*)(bp_ + 0 * 512 + ln * 8);                     \
        v8s bf1_ = *(const v8s*)(bp_ + 1 * 512 + ln * 8);                     \
        v8s bf2_ = *(const v8s*)(bp_ + 2 * 512 + ln * 8);                     \
        v8s bf3_ = *(const v8s*)(bp_ + 3 * 512 + ln * 8);                     \
        const float* dd_ = dtb + (JC_) * 64;                                  \
        v8s afr_;                                                             \
        GENFRAG(afr_, M_, dd_);                                               \
        acc0 = __builtin_amdgcn_mfma_f32_16x16x32_bf16(afr_, bf0_, acc0, 0, 0, 0); \
        acc1 = __builtin_amdgcn_mfma_f32_16x16x32_bf16(afr_, bf1_, acc1, 0, 0, 0); \
        acc2 = __builtin_amdgcn_mfma_f32_16x16x32_bf16(afr_, bf2_, acc2, 0, 0, 0); \
        acc3 = __builtin_amdgcn_mfma_f32_16x16x32_bf16(afr_, bf3_, acc3, 0, 0, 0); \
        zac  = __builtin_amdgcn_mfma_f32_16x16x32_bf16(afr_, ones, zac,  0, 0, 0); \
    } while (0)

    // ---- prologue: stage super-round 0 (regions jc=0..3) into buf0 ----
    stg0 = *(const uint4*)(sb2 + (size_t)ri * 8192);
    stg1 = *(const uint4*)(sb2 + (size_t)ri * 8192 + 8);
    mA = ajr[jp * 4 + l4];
    mB = ajr[(2 + jp) * 4 + l4];
    *(uint4*)&Btile[0][ri][soff]     = stg0;   // compiler waits vmcnt
    *(uint4*)&Btile[0][ri][soff + 8] = stg1;
    __syncthreads();                           // buf0 + dtab ready

#pragma unroll 1
    for (int sr = 0; sr < 16; ++sr) {
        const int buf = sr & 1;
        // ---- issue next super-round's loads (covered by 2 compute rounds)
        const int jq = ((sr + 1) & 15) * 4;
        stg0 = *(const uint4*)(sb2 + (size_t)(jq + ri) * 8192);
        stg1 = *(const uint4*)(sb2 + (size_t)(jq + ri) * 8192 + 8);
        const unsigned mA2 = ajr[(jq + jp) * 4 + l4];
        const unsigned mB2 = ajr[(jq + 2 + jp) * 4 + l4];
        __builtin_amdgcn_sched_barrier(0);     // pin loads above compute
        // ---- compute 2 rounds from buf ----
        COMPUTE(4 * sr + jp,     mA, Btile[buf][jp]);
        COMPUTE(4 * sr + 2 + jp, mB, Btile[buf][2 + jp]);
        // ---- land staged data (vmcnt wait here, after compute) ----
        *(uint4*)&Btile[buf ^ 1][ri][soff]     = stg0;
        *(uint4*)&Btile[buf ^ 1][ri][soff + 8] = stg1;
        mA = mA2; mB = mB2;
        __syncthreads();
    }

#undef GENFRAG
#undef COMPUTE

    // ---- jp-combine via LDS; jp=0 waves normalize + exclusive store ----
    if (jp) {
        float* rp = &red[isub][ln][0];
        *(v4f*)(rp + 0)  = acc0;
        *(v4f*)(rp + 4)  = acc1;
        *(v4f*)(rp + 8)  = acc2;
        *(v4f*)(rp + 12) = acc3;
        *(v4f*)(rp + 16) = zac;
    }
    __syncthreads();
    if (!jp) {
        const float* rp = &red[isub][ln][0];
        acc0 += *(const v4f*)(rp + 0);
        acc1 += *(const v4f*)(rp + 4);
        acc2 += *(const v4f*)(rp + 8);
        acc3 += *(const v4f*)(rp + 12);
        zac  += *(const v4f*)(rp + 16);
        float* op = out + ((size_t)b * Nn + i0 + isub * 16 + l4 * 4) * Dd + h * HDd + l15;
#pragma unroll
        for (int r = 0; r < 4; ++r) {
            float zi = 1.f / zac[r];
            op[(size_t)r * Dd + 0]  = acc0[r] * zi;
            op[(size_t)r * Dd + 16] = acc1[r] * zi;
            op[(size_t)r * Dd + 32] = acc2[r] * zi;
            op[(size_t)r * Dd + 48] = acc3[r] * zi;
        }
    }
}

extern "C" void kernel_launch(void* const* d_in, const int* in_sizes, int n_in,
                              void* d_out, int out_size, void* d_ws, size_t ws_size,
                              hipStream_t stream) {
    const float* x     = (const float*)d_in[0];
    const float* adj   = (const float*)d_in[1];
    const float* W     = (const float*)d_in[2];
    const float* a_src = (const float*)d_in[3];
    const float* a_dst = (const float*)d_in[4];
    float* out = (float*)d_out;

    // ws: hbf 4MB | ssrc [h][bn] 128KB | sdst [h][bn] 128KB | bitadj 2MB
    unsigned short* hbf = (unsigned short*)d_ws;
    float* ssrc = (float*)(hbf + (size_t)Bb * Nn * Dd);
    float* sdst = ssrc + (size_t)Hh * BN;
    unsigned long long* bitadj = (unsigned long long*)(sdst + (size_t)Hh * BN);

    k_gemm<<<dim3(1024), dim3(256), 0, stream>>>(x, W, a_src, a_dst, adj,
                                                 hbf, ssrc, sdst, bitadj);
    k_aggr<<<dim3(512), dim3(512), 0, stream>>>(hbf, bitadj, ssrc, sdst, out);
}